// Round 12
// baseline (4181.482 us; speedup 1.0000x reference)
//
#include <hip/hip_runtime.h>

// Bit-exact emulation of the fp32 gold, round 12 model: kc=512 panel family.
//  - GEMMs: K split {512,512,512,512}. Per C element: sequential
//    single-accumulator fmaf chain per panel (k ascending); panel sums added
//    into C ascending with one fp32 rounding each; first panel exact.
//    Covers: AOCL-BLIS zen4/zen5 sgemm (KC=512, 6x64 AVX-512 ukernel),
//    hipBLASLt/Tensile GSU=4 split-K (per-thread chains + ordered fix-up),
//    MKL kc=512 AVX-512 paths.
//  - Elementwise: one individually-rounded fp32 op per ufunc; contract(off).
// Falsified: fp64; fmaf panels {2048},{384x4,256x2},{384x5,128},
// {320x5,224x2},{320x6,128},{288x7,32},{256x8}; mul+add panels
// {320x6,128},{288x7,32}.

#pragma clang fp contract(off)

#define B_ROWS 512
#define N_OUT 2048
#define K_IN 2048
#define NSTEP 16
#define RPB 8   // batch rows per thread

#define NPAN 4
static constexpr int PANELS[NPAN + 1] = {0, 512, 1024, 1536, 2048};

// ---- 32x32 LDS-tiled transpose: WT[k][n] = W[n][k] (*mask) ----
__global__ __launch_bounds__(256) void transpose_tile(
    const float* __restrict__ W, const int* __restrict__ mask,
    float* __restrict__ WT, int useMask)
{
    __shared__ float t[32][33];
    int kb = blockIdx.x * 32, nb = blockIdx.y * 32;
    int tx = threadIdx.x, ty = threadIdx.y;   // block (32, 8)
#pragma unroll
    for (int r = 0; r < 32; r += 8) {
        size_t src = (size_t)(nb + ty + r) * K_IN + (kb + tx);
        float v = W[src];
        if (useMask) v *= (float)mask[src];   // mask in {0,1}: exact
        t[ty + r][tx] = v;
    }
    __syncthreads();
#pragma unroll
    for (int r = 0; r < 32; r += 8)
        WT[(size_t)(kb + ty + r) * N_OUT + (nb + tx)] = t[tx][ty + r];
}

__global__ __launch_bounds__(256) void init_state(float* mem, float* ath,
                                                  float* ssum, float* spk) {
    int idx = blockIdx.x * 256 + threadIdx.x;
    mem[idx] = 0.0f; ath[idx] = 0.0f; ssum[idx] = 0.0f; spk[idx] = 0.0f;
}

// ---- ff[b][n] = kc512-model(x @ WT) + b_fc[n] ----
__global__ __launch_bounds__(256) void ff_f32(
    const float* __restrict__ x, const float* __restrict__ WT,
    const float* __restrict__ b_fc, float* __restrict__ ff)
{
    int n = blockIdx.x * 256 + threadIdx.x;
    int b0 = blockIdx.y * RPB;
    float C[RPB];
#pragma unroll
    for (int p = 0; p < NPAN; p++) {
        float s[RPB];
#pragma unroll
        for (int i = 0; i < RPB; i++) s[i] = 0.0f;
#pragma unroll 4
        for (int k = PANELS[p]; k < PANELS[p + 1]; k++) {
            float w = WT[(size_t)k * N_OUT + n];        // coalesced
#pragma unroll
            for (int i = 0; i < RPB; i++)               // x: wave-uniform
                s[i] = fmaf(x[(size_t)(b0 + i) * K_IN + k], w, s[i]);
        }
#pragma unroll
        for (int i = 0; i < RPB; i++)
            C[i] = (p == 0) ? s[i] : (C[i] + s[i]);     // one rounding/panel
    }
#pragma unroll
    for (int i = 0; i < RPB; i++)
        ff[(size_t)(b0 + i) * N_OUT + n] = C[i] + b_fc[n];
}

// ---- one step: memr = kc512-model(spk @ WrT) + fused fp32 SNN update ----
__global__ __launch_bounds__(256) void step_f32(
    const float* __restrict__ spk_in, const float* __restrict__ WT,
    const float* __restrict__ ff, const float* __restrict__ b_rec,
    float* __restrict__ mem, float* __restrict__ ath,
    float* __restrict__ ssum, float* __restrict__ spk_out,
    float* __restrict__ out, int last)
{
    int n = blockIdx.x * 256 + threadIdx.x;
    int b0 = blockIdx.y * RPB;
    float C[RPB];
#pragma unroll
    for (int p = 0; p < NPAN; p++) {
        float s[RPB];
#pragma unroll
        for (int i = 0; i < RPB; i++) s[i] = 0.0f;
#pragma unroll 4
        for (int k = PANELS[p]; k < PANELS[p + 1]; k++) {
            float w = WT[(size_t)k * N_OUT + n];        // coalesced
#pragma unroll
            for (int i = 0; i < RPB; i++)               // spk: wave-uniform
                s[i] = fmaf(spk_in[(size_t)(b0 + i) * N_OUT + k], w, s[i]);
        }
#pragma unroll
        for (int i = 0; i < RPB; i++)
            C[i] = (p == 0) ? s[i] : (C[i] + s[i]);
    }

#pragma unroll
    for (int i = 0; i < RPB; i++) {
        int b = b0 + i;
        size_t idx = (size_t)b * N_OUT + n;
        float memr   = C[i] + b_rec[n];          // rounded add
        float s      = spk_in[idx];              // prev spike at (b,n)
        float t1     = ath[idx] * 0.9f;          // rounded
        float t2     = 0.5f * s;                 // exact
        float athn   = t1 + t2;                  // rounded
        float u1     = mem[idx] * 0.2f;          // rounded
        float u2     = 1.0f - s;                 // exact {1,0,-1}
        float u3     = u1 * u2;                  // exact (sign/zero flip)
        float u4     = u3 + ff[idx];             // rounded
        float u5     = athn * 0.2f;              // rounded
        float memff  = u4 - u5;                  // rounded
        float s_ff   = (memff > 0.5f) ? 1.0f : 0.0f;
        float s_r    = (memr  > 0.5f) ? 1.0f : 0.0f;
        float memn   = memff + memr;             // rounded
        float spkn   = s_ff + s_r;               // exact
        float ss     = ssum[idx] + spkn;         // exact (small ints)

        mem[idx] = memn;
        ath[idx] = athn;
        ssum[idx] = ss;
        spk_out[idx] = spkn;
        if (last) out[idx] = ss;
    }
}

extern "C" void kernel_launch(void* const* d_in, const int* in_sizes, int n_in,
                              void* d_out, int out_size, void* d_ws, size_t ws_size,
                              hipStream_t stream) {
    const float* x      = (const float*)d_in[0];
    const float* W_fc   = (const float*)d_in[1];
    const float* b_fc   = (const float*)d_in[2];
    const float* W_rec  = (const float*)d_in[3];
    const float* b_rec  = (const float*)d_in[4];
    const int*   rmask  = (const int*)d_in[5];
    // d_in[6] = spike_window (16)

    char* ws = (char*)d_ws;
    float* WT   = (float*)(ws);                    // 16 MB (fc, then rec)
    float* ff   = (float*)(ws + (16u << 20));      //  4 MB
    float* mem  = (float*)(ws + (20u << 20));      //  4 MB
    float* ath  = (float*)(ws + (24u << 20));      //  4 MB
    float* ssum = (float*)(ws + (28u << 20));      //  4 MB
    float* spkA = (float*)(ws + (32u << 20));      //  4 MB
    float* spkB = (float*)(ws + (36u << 20));      //  4 MB (total 40 MB)

    dim3 gridT(K_IN / 32, N_OUT / 32);             // (64, 64)
    dim3 blkT(32, 8);
    dim3 gridS((B_ROWS * N_OUT) / 256);            // 4096
    dim3 gridG(N_OUT / 256, B_ROWS / RPB);         // (8, 64)

    transpose_tile<<<gridT, blkT, 0, stream>>>(W_fc, rmask, WT, 0);
    init_state<<<gridS, 256, 0, stream>>>(mem, ath, ssum, spkA);
    ff_f32<<<gridG, 256, 0, stream>>>(x, WT, b_fc, ff);
    transpose_tile<<<gridT, blkT, 0, stream>>>(W_rec, rmask, WT, 1);

    for (int t = 0; t < NSTEP; t++) {
        const float* si = (t & 1) ? spkB : spkA;
        float*       so = (t & 1) ? spkA : spkB;
        step_f32<<<gridG, 256, 0, stream>>>(
            si, WT, ff, b_rec, mem, ath, ssum, so, (float*)d_out, t == NSTEP - 1);
    }
}

// Round 13
// 2583.451 us; speedup vs baseline: 1.6186x; 1.6186x over previous
//
#include <hip/hip_runtime.h>

// Bit-exact gold model (VERIFIED round 12, absmax=0): per C element the GEMM
// is 4 panels of 512 sequential fmaf's (k ascending, one accumulator), panel
// sums folded into C ascending (first exact); elementwise = one rounded fp32
// op per ufunc, contract(off).
// This round: same arithmetic, restructured as an LDS-tiled GEMM (tiling M/N
// and staging never changes per-element rounding; k order and single-acc
// chain preserved). BM=32 BN=64 BK=64, 2x4 microtile, reg-prefetch pipeline.

#pragma clang fp contract(off)

#define B_ROWS 512
#define N_OUT 2048
#define K_IN 2048
#define NSTEP 16

#define BM 32
#define BN 64
#define BKT 64
#define NT (K_IN / BKT)       // 32 k-tiles
#define TPP (512 / BKT)       // 8 tiles per 512-panel
#define LDA_PAD (BKT + 4)     // As stride 68: 16B-aligned rows
#define LDB_PAD (BN + 4)      // Bs stride 68

// ---- 32x32 LDS-tiled transpose: WT[k][n] = W[n][k] (*mask) ----
__global__ __launch_bounds__(256) void transpose_tile(
    const float* __restrict__ W, const int* __restrict__ mask,
    float* __restrict__ WT, int useMask)
{
    __shared__ float t[32][33];
    int kb = blockIdx.x * 32, nb = blockIdx.y * 32;
    int tx = threadIdx.x, ty = threadIdx.y;   // block (32, 8)
#pragma unroll
    for (int r = 0; r < 32; r += 8) {
        size_t src = (size_t)(nb + ty + r) * K_IN + (kb + tx);
        float v = W[src];
        if (useMask) v *= (float)mask[src];   // mask in {0,1}: exact
        t[ty + r][tx] = v;
    }
    __syncthreads();
#pragma unroll
    for (int r = 0; r < 32; r += 8)
        WT[(size_t)(kb + ty + r) * N_OUT + (nb + tx)] = t[tx][ty + r];
}

__global__ __launch_bounds__(256) void init_state(float* mem, float* ath,
                                                  float* ssum, float* spk) {
    int idx = blockIdx.x * 256 + threadIdx.x;
    mem[idx] = 0.0f; ath[idx] = 0.0f; ssum[idx] = 0.0f; spk[idx] = 0.0f;
}

// ---------------- shared GEMM machinery (bit-exact chain) -----------------
// A: [B_ROWS][2048] row-major (x or spk). BT: [2048][N_OUT] (WT).
// Thread layout: tx = tid&15 -> n chunk of 4; ty = tid>>4 -> m chunk of 2.
// Staging: sr = tid>>4 (row group), sc = (tid&15)*4 (16B chunk).

#define GEMM_BODY(A_PTR, BT_PTR)                                              \
    __shared__ float As[BM][LDA_PAD];                                         \
    __shared__ float Bs[BKT][LDB_PAD];                                        \
    const int tid = threadIdx.x;                                              \
    const int tx4 = (tid & 15) * 4;                                           \
    const int ty2 = (tid >> 4) * 2;                                           \
    const int bn = blockIdx.x * BN;                                           \
    const int bm = blockIdx.y * BM;                                           \
    const int sr = tid >> 4;                                                  \
    const int sc = (tid & 15) * 4;                                            \
    float C[2][4], s[2][4];                                                   \
    float4 pa[2], pb[4];                                                      \
    _Pragma("unroll")                                                         \
    for (int i = 0; i < 2; i++)                                               \
        _Pragma("unroll")                                                     \
        for (int j = 0; j < 4; j++) s[i][j] = 0.0f;                           \
    /* load tile 0 */                                                         \
    pa[0] = *(const float4*)(A_PTR + (size_t)(bm + sr) * 2048 + sc);          \
    pa[1] = *(const float4*)(A_PTR + (size_t)(bm + sr + 16) * 2048 + sc);     \
    _Pragma("unroll")                                                         \
    for (int it = 0; it < 4; it++)                                            \
        pb[it] = *(const float4*)(BT_PTR + (size_t)(sr + 16 * it) * N_OUT + bn + sc); \
    *(float4*)&As[sr][sc] = pa[0];                                            \
    *(float4*)&As[sr + 16][sc] = pa[1];                                       \
    _Pragma("unroll")                                                         \
    for (int it = 0; it < 4; it++)                                            \
        *(float4*)&Bs[sr + 16 * it][sc] = pb[it];                             \
    __syncthreads();                                                          \
    for (int t = 0; t < NT; t++) {                                            \
        if (t + 1 < NT) {                                                     \
            int k0 = (t + 1) * BKT;                                           \
            pa[0] = *(const float4*)(A_PTR + (size_t)(bm + sr) * 2048 + k0 + sc);      \
            pa[1] = *(const float4*)(A_PTR + (size_t)(bm + sr + 16) * 2048 + k0 + sc); \
            _Pragma("unroll")                                                 \
            for (int it = 0; it < 4; it++)                                    \
                pb[it] = *(const float4*)(BT_PTR + (size_t)(k0 + sr + 16 * it) * N_OUT + bn + sc); \
        }                                                                     \
        _Pragma("unroll 8")                                                   \
        for (int kk = 0; kk < BKT; kk++) {                                    \
            float a0 = As[ty2][kk];                                           \
            float a1 = As[ty2 + 1][kk];                                       \
            float4 b = *(const float4*)&Bs[kk][tx4];                          \
            s[0][0] = fmaf(a0, b.x, s[0][0]);                                 \
            s[0][1] = fmaf(a0, b.y, s[0][1]);                                 \
            s[0][2] = fmaf(a0, b.z, s[0][2]);                                 \
            s[0][3] = fmaf(a0, b.w, s[0][3]);                                 \
            s[1][0] = fmaf(a1, b.x, s[1][0]);                                 \
            s[1][1] = fmaf(a1, b.y, s[1][1]);                                 \
            s[1][2] = fmaf(a1, b.z, s[1][2]);                                 \
            s[1][3] = fmaf(a1, b.w, s[1][3]);                                 \
        }                                                                     \
        if (t + 1 < NT) {                                                     \
            __syncthreads();                                                  \
            *(float4*)&As[sr][sc] = pa[0];                                    \
            *(float4*)&As[sr + 16][sc] = pa[1];                               \
            _Pragma("unroll")                                                 \
            for (int it = 0; it < 4; it++)                                    \
                *(float4*)&Bs[sr + 16 * it][sc] = pb[it];                     \
            __syncthreads();                                                  \
        }                                                                     \
        if ((t & (TPP - 1)) == (TPP - 1)) {   /* 512-panel boundary */        \
            _Pragma("unroll")                                                 \
            for (int i = 0; i < 2; i++)                                       \
                _Pragma("unroll")                                             \
                for (int j = 0; j < 4; j++) {                                 \
                    C[i][j] = (t < TPP) ? s[i][j] : (C[i][j] + s[i][j]);      \
                    s[i][j] = 0.0f;                                           \
                }                                                             \
        }                                                                     \
    }

// ---- ff[b][n] = panel-model(x @ WT) + b_fc[n] ----
__global__ __launch_bounds__(256) void ff_gemm(
    const float* __restrict__ x, const float* __restrict__ WT,
    const float* __restrict__ b_fc, float* __restrict__ ff)
{
    GEMM_BODY(x, WT)
#pragma unroll
    for (int i = 0; i < 2; i++) {
        int b = bm + ty2 + i;
        float4 bias = *(const float4*)(b_fc + bn + tx4);
        float4 o;
        o.x = C[i][0] + bias.x;
        o.y = C[i][1] + bias.y;
        o.z = C[i][2] + bias.z;
        o.w = C[i][3] + bias.w;
        *(float4*)(ff + (size_t)b * N_OUT + bn + tx4) = o;
    }
}

// ---- one step: memr = panel-model(spk @ WrT) + fused fp32 SNN update ----
__global__ __launch_bounds__(256) void step_f32(
    const float* __restrict__ spk_in, const float* __restrict__ WT,
    const float* __restrict__ ff, const float* __restrict__ b_rec,
    float* __restrict__ mem, float* __restrict__ ath,
    float* __restrict__ ssum, float* __restrict__ spk_out,
    float* __restrict__ out, int last)
{
    GEMM_BODY(spk_in, WT)
    float4 bias = *(const float4*)(b_rec + bn + tx4);
#pragma unroll
    for (int i = 0; i < 2; i++) {
        int b = bm + ty2 + i;
        size_t rowoff = (size_t)b * N_OUT + bn + tx4;
        float4 sv  = *(const float4*)(spk_in + rowoff);
        float4 av  = *(const float4*)(ath + rowoff);
        float4 mv  = *(const float4*)(mem + rowoff);
        float4 fv  = *(const float4*)(ff + rowoff);
        float4 uv  = *(const float4*)(ssum + rowoff);
        float memr_[4] = {C[i][0] + bias.x, C[i][1] + bias.y,
                          C[i][2] + bias.z, C[i][3] + bias.w};
        float sarr[4] = {sv.x, sv.y, sv.z, sv.w};
        float aarr[4] = {av.x, av.y, av.z, av.w};
        float marr[4] = {mv.x, mv.y, mv.z, mv.w};
        float farr[4] = {fv.x, fv.y, fv.z, fv.w};
        float uarr[4] = {uv.x, uv.y, uv.z, uv.w};
        float mo[4], ao[4], uo[4], so[4];
#pragma unroll
        for (int j = 0; j < 4; j++) {
            float memr = memr_[j];
            float sp   = sarr[j];
            float t1   = aarr[j] * 0.9f;      // rounded
            float t2   = 0.5f * sp;           // exact
            float athn = t1 + t2;             // rounded
            float u1   = marr[j] * 0.2f;      // rounded
            float u2   = 1.0f - sp;           // exact
            float u3   = u1 * u2;             // exact (sign/zero)
            float u4   = u3 + farr[j];        // rounded
            float u5   = athn * 0.2f;         // rounded
            float memff = u4 - u5;            // rounded
            float s_ff = (memff > 0.5f) ? 1.0f : 0.0f;
            float s_r  = (memr  > 0.5f) ? 1.0f : 0.0f;
            mo[j] = memff + memr;             // rounded
            ao[j] = athn;
            so[j] = s_ff + s_r;               // exact
            uo[j] = uarr[j] + so[j];          // exact
        }
        *(float4*)(mem + rowoff)     = make_float4(mo[0], mo[1], mo[2], mo[3]);
        *(float4*)(ath + rowoff)     = make_float4(ao[0], ao[1], ao[2], ao[3]);
        *(float4*)(ssum + rowoff)    = make_float4(uo[0], uo[1], uo[2], uo[3]);
        *(float4*)(spk_out + rowoff) = make_float4(so[0], so[1], so[2], so[3]);
        if (last)
            *(float4*)(out + rowoff) = make_float4(uo[0], uo[1], uo[2], uo[3]);
    }
}

extern "C" void kernel_launch(void* const* d_in, const int* in_sizes, int n_in,
                              void* d_out, int out_size, void* d_ws, size_t ws_size,
                              hipStream_t stream) {
    const float* x      = (const float*)d_in[0];
    const float* W_fc   = (const float*)d_in[1];
    const float* b_fc   = (const float*)d_in[2];
    const float* W_rec  = (const float*)d_in[3];
    const float* b_rec  = (const float*)d_in[4];
    const int*   rmask  = (const int*)d_in[5];
    // d_in[6] = spike_window (16)

    char* ws = (char*)d_ws;
    float* WT   = (float*)(ws);                    // 16 MB (fc, then rec)
    float* ff   = (float*)(ws + (16u << 20));      //  4 MB
    float* mem  = (float*)(ws + (20u << 20));      //  4 MB
    float* ath  = (float*)(ws + (24u << 20));      //  4 MB
    float* ssum = (float*)(ws + (28u << 20));      //  4 MB
    float* spkA = (float*)(ws + (32u << 20));      //  4 MB
    float* spkB = (float*)(ws + (36u << 20));      //  4 MB (total 40 MB)

    dim3 gridT(K_IN / 32, N_OUT / 32);             // (64, 64)
    dim3 blkT(32, 8);
    dim3 gridS((B_ROWS * N_OUT) / 256);            // 4096
    dim3 gridG(N_OUT / BN, B_ROWS / BM);           // (32, 16) = 512 blocks

    transpose_tile<<<gridT, blkT, 0, stream>>>(W_fc, rmask, WT, 0);
    init_state<<<gridS, 256, 0, stream>>>(mem, ath, ssum, spkA);
    ff_gemm<<<gridG, 256, 0, stream>>>(x, WT, b_fc, ff);
    transpose_tile<<<gridT, blkT, 0, stream>>>(W_rec, rmask, WT, 1);

    for (int t = 0; t < NSTEP; t++) {
        const float* si = (t & 1) ? spkB : spkA;
        float*       so = (t & 1) ? spkA : spkB;
        step_f32<<<gridG, 256, 0, stream>>>(
            si, WT, ff, b_rec, mem, ath, ssum, so, (float*)d_out, t == NSTEP - 1);
    }
}

// Round 14
// 1389.119 us; speedup vs baseline: 3.0102x; 1.8598x over previous
//
#include <hip/hip_runtime.h>

// Bit-exact gold model (VERIFIED rounds 12-13, absmax=0): per C element the
// GEMM is 4 panels of 512 sequential fmaf's (k ascending, single acc); panel
// sums folded ((p0+p1)+p2)+p3; then bias add; elementwise = one rounded fp32
// op per ufunc, contract(off).
// Round 14: split-K x4 across blockIdx.z (panels are independent chains ->
// bit-exact with ordered fold), 8x8 microtile to cut LDS bytes/FMA from
// 2.95 to 1.0 (round-13 was LDS-pipe-bound at 21% VALUBusy).

#pragma clang fp contract(off)

#define B_ROWS 512
#define N_OUT 2048
#define K_IN 2048
#define NSTEP 16
#define NPANEL 4
#define PANK 512
#define BK 16
#define TM 64
#define TN 128
#define ASTR 68    // As row stride (64 m + pad)
#define BSTR 132   // Bs row stride (128 n + pad)
#define NTILES (PANK / BK)   // 32

// ---- 32x32 LDS-tiled transpose: WT[k][n] = W[n][k] (*mask) ----
__global__ __launch_bounds__(256) void transpose_tile(
    const float* __restrict__ W, const int* __restrict__ mask,
    float* __restrict__ WT, int useMask)
{
    __shared__ float t[32][33];
    int kb = blockIdx.x * 32, nb = blockIdx.y * 32;
    int tx = threadIdx.x, ty = threadIdx.y;   // block (32, 8)
#pragma unroll
    for (int r = 0; r < 32; r += 8) {
        size_t src = (size_t)(nb + ty + r) * K_IN + (kb + tx);
        float v = W[src];
        if (useMask) v *= (float)mask[src];   // mask in {0,1}: exact
        t[ty + r][tx] = v;
    }
    __syncthreads();
#pragma unroll
    for (int r = 0; r < 32; r += 8)
        WT[(size_t)(kb + ty + r) * N_OUT + (nb + tx)] = t[tx][ty + r];
}

__global__ __launch_bounds__(256) void init_state(float* mem, float* ath,
                                                  float* ssum, float* spk) {
    int idx = blockIdx.x * 256 + threadIdx.x;
    mem[idx] = 0.0f; ath[idx] = 0.0f; ssum[idx] = 0.0f; spk[idx] = 0.0f;
}

// ---- one K-panel of C = A @ BT : Cp[panel][m][n], bit-exact 512-chain ----
__global__ __launch_bounds__(128) void gemm_panel(
    const float* __restrict__ A,    // [512][2048] (x or spk)
    const float* __restrict__ BT,   // [2048][2048] (WT)
    float* __restrict__ Cp)         // [4][512][2048]
{
    __shared__ float As[2][BK][ASTR];   // k-major: As[buf][k][m]
    __shared__ float Bs[2][BK][BSTR];   // Bs[buf][k][n]
    const int tid = threadIdx.x;
    const int tx = tid & 15;            // n group: 8 cols
    const int ty = tid >> 4;            // m group: 8 rows (0..7)
    const int n0 = blockIdx.x * TN;
    const int m0 = blockIdx.y * TM;
    const int pan = blockIdx.z;
    const int kbase = pan * PANK;

    const int sa_m = tid >> 1;          // 0..63
    const int sa_k = (tid & 1) * 8;     // 0 / 8
    const int sb_k = tid >> 3;          // 0..15
    const int sb_n = (tid & 7) * 16;    // 0..112

    float acc[8][8];
#pragma unroll
    for (int i = 0; i < 8; i++)
#pragma unroll
        for (int j = 0; j < 8; j++) acc[i][j] = 0.0f;

    const float* Abase = A + (size_t)(m0 + sa_m) * K_IN + kbase + sa_k;
    const float* Bbase = BT + (size_t)(kbase + sb_k) * N_OUT + n0 + sb_n;

    float4 ra0, ra1, rb0, rb1, rb2, rb3;
    ra0 = *(const float4*)(Abase);
    ra1 = *(const float4*)(Abase + 4);
    rb0 = *(const float4*)(Bbase);
    rb1 = *(const float4*)(Bbase + 4);
    rb2 = *(const float4*)(Bbase + 8);
    rb3 = *(const float4*)(Bbase + 12);
    {
        float av[8] = {ra0.x, ra0.y, ra0.z, ra0.w, ra1.x, ra1.y, ra1.z, ra1.w};
#pragma unroll
        for (int j = 0; j < 8; j++) As[0][sa_k + j][sa_m] = av[j];
        *(float4*)&Bs[0][sb_k][sb_n]      = rb0;
        *(float4*)&Bs[0][sb_k][sb_n + 4]  = rb1;
        *(float4*)&Bs[0][sb_k][sb_n + 8]  = rb2;
        *(float4*)&Bs[0][sb_k][sb_n + 12] = rb3;
    }
    __syncthreads();

    int buf = 0;
    for (int kt = 0; kt < NTILES; kt++) {
        if (kt + 1 < NTILES) {
            const float* Ab = Abase + (kt + 1) * BK;
            const float* Bb = Bbase + (size_t)(kt + 1) * BK * N_OUT;
            ra0 = *(const float4*)(Ab);
            ra1 = *(const float4*)(Ab + 4);
            rb0 = *(const float4*)(Bb);
            rb1 = *(const float4*)(Bb + 4);
            rb2 = *(const float4*)(Bb + 8);
            rb3 = *(const float4*)(Bb + 12);
        }
#pragma unroll
        for (int kk = 0; kk < BK; kk++) {
            float4 a0 = *(const float4*)&As[buf][kk][ty * 8];
            float4 a1 = *(const float4*)&As[buf][kk][ty * 8 + 4];
            float4 b0 = *(const float4*)&Bs[buf][kk][tx * 8];
            float4 b1 = *(const float4*)&Bs[buf][kk][tx * 8 + 4];
            float aa[8] = {a0.x, a0.y, a0.z, a0.w, a1.x, a1.y, a1.z, a1.w};
            float bb[8] = {b0.x, b0.y, b0.z, b0.w, b1.x, b1.y, b1.z, b1.w};
#pragma unroll
            for (int i = 0; i < 8; i++)
#pragma unroll
                for (int j = 0; j < 8; j++)
                    acc[i][j] = fmaf(aa[i], bb[j], acc[i][j]);
        }
        if (kt + 1 < NTILES) {
            __syncthreads();   // all waves done reading buf^1 (and buf this kt)
            float av[8] = {ra0.x, ra0.y, ra0.z, ra0.w, ra1.x, ra1.y, ra1.z, ra1.w};
#pragma unroll
            for (int j = 0; j < 8; j++) As[buf ^ 1][sa_k + j][sa_m] = av[j];
            *(float4*)&Bs[buf ^ 1][sb_k][sb_n]      = rb0;
            *(float4*)&Bs[buf ^ 1][sb_k][sb_n + 4]  = rb1;
            *(float4*)&Bs[buf ^ 1][sb_k][sb_n + 8]  = rb2;
            *(float4*)&Bs[buf ^ 1][sb_k][sb_n + 12] = rb3;
            __syncthreads();
            buf ^= 1;
        }
    }

#pragma unroll
    for (int i = 0; i < 8; i++) {
        int row = m0 + ty * 8 + i;
        size_t off = (size_t)pan * (B_ROWS * N_OUT) + (size_t)row * N_OUT + n0 + tx * 8;
        *(float4*)(Cp + off)     = make_float4(acc[i][0], acc[i][1], acc[i][2], acc[i][3]);
        *(float4*)(Cp + off + 4) = make_float4(acc[i][4], acc[i][5], acc[i][6], acc[i][7]);
    }
}

// ---- ff = fold(Cp) + b_fc  (bit-exact ordered fold) ----
__global__ __launch_bounds__(256) void ff_fold(
    const float* __restrict__ Cp, const float* __restrict__ b_fc,
    float* __restrict__ ff)
{
    const size_t P = (size_t)B_ROWS * N_OUT;
    size_t base = ((size_t)blockIdx.x * 256 + threadIdx.x) * 4;
    int n = (int)(base & (N_OUT - 1));
    float4 p0 = *(const float4*)(Cp + base);
    float4 p1 = *(const float4*)(Cp + P + base);
    float4 p2 = *(const float4*)(Cp + 2 * P + base);
    float4 p3 = *(const float4*)(Cp + 3 * P + base);
    float4 bv = *(const float4*)(b_fc + n);
    float4 o;
    o.x = ((p0.x + p1.x) + p2.x) + p3.x + 0.0f;
    o.x = (((p0.x + p1.x) + p2.x) + p3.x) + bv.x;
    o.y = (((p0.y + p1.y) + p2.y) + p3.y) + bv.y;
    o.z = (((p0.z + p1.z) + p2.z) + p3.z) + bv.z;
    o.w = (((p0.w + p1.w) + p2.w) + p3.w) + bv.w;
    *(float4*)(ff + base) = o;
}

// ---- fold(Cp) + b_rec -> memr, then fused fp32 SNN elementwise update ----
__global__ __launch_bounds__(256) void fold_update(
    const float* __restrict__ Cp, const float* __restrict__ b_rec,
    const float* __restrict__ spk_in, const float* __restrict__ ff,
    float* __restrict__ mem, float* __restrict__ ath,
    float* __restrict__ ssum, float* __restrict__ spk_out,
    float* __restrict__ out, int last)
{
    const size_t P = (size_t)B_ROWS * N_OUT;
    size_t base = ((size_t)blockIdx.x * 256 + threadIdx.x) * 4;
    int n = (int)(base & (N_OUT - 1));
    float4 p0 = *(const float4*)(Cp + base);
    float4 p1 = *(const float4*)(Cp + P + base);
    float4 p2 = *(const float4*)(Cp + 2 * P + base);
    float4 p3 = *(const float4*)(Cp + 3 * P + base);
    float4 bv = *(const float4*)(b_rec + n);
    float4 sv = *(const float4*)(spk_in + base);
    float4 av = *(const float4*)(ath + base);
    float4 mv = *(const float4*)(mem + base);
    float4 fv = *(const float4*)(ff + base);
    float4 uv = *(const float4*)(ssum + base);

    float cr[4] = {(((p0.x + p1.x) + p2.x) + p3.x),
                   (((p0.y + p1.y) + p2.y) + p3.y),
                   (((p0.z + p1.z) + p2.z) + p3.z),
                   (((p0.w + p1.w) + p2.w) + p3.w)};
    float ba[4] = {bv.x, bv.y, bv.z, bv.w};
    float sa[4] = {sv.x, sv.y, sv.z, sv.w};
    float aa[4] = {av.x, av.y, av.z, av.w};
    float ma[4] = {mv.x, mv.y, mv.z, mv.w};
    float fa[4] = {fv.x, fv.y, fv.z, fv.w};
    float ua[4] = {uv.x, uv.y, uv.z, uv.w};
    float mo[4], ao[4], uo[4], so[4];
#pragma unroll
    for (int j = 0; j < 4; j++) {
        float memr  = cr[j] + ba[j];      // rounded add
        float sp    = sa[j];
        float t1    = aa[j] * 0.9f;       // rounded
        float t2    = 0.5f * sp;          // exact
        float athn  = t1 + t2;            // rounded
        float u1    = ma[j] * 0.2f;       // rounded
        float u2    = 1.0f - sp;          // exact {1,0,-1}
        float u3    = u1 * u2;            // exact (sign/zero)
        float u4    = u3 + fa[j];         // rounded
        float u5    = athn * 0.2f;        // rounded
        float memff = u4 - u5;            // rounded
        float s_ff  = (memff > 0.5f) ? 1.0f : 0.0f;
        float s_r   = (memr  > 0.5f) ? 1.0f : 0.0f;
        mo[j] = memff + memr;             // rounded
        ao[j] = athn;
        so[j] = s_ff + s_r;               // exact
        uo[j] = ua[j] + so[j];            // exact (small ints)
    }
    *(float4*)(mem + base)     = make_float4(mo[0], mo[1], mo[2], mo[3]);
    *(float4*)(ath + base)     = make_float4(ao[0], ao[1], ao[2], ao[3]);
    *(float4*)(ssum + base)    = make_float4(uo[0], uo[1], uo[2], uo[3]);
    *(float4*)(spk_out + base) = make_float4(so[0], so[1], so[2], so[3]);
    if (last)
        *(float4*)(out + base) = make_float4(uo[0], uo[1], uo[2], uo[3]);
}

extern "C" void kernel_launch(void* const* d_in, const int* in_sizes, int n_in,
                              void* d_out, int out_size, void* d_ws, size_t ws_size,
                              hipStream_t stream) {
    const float* x      = (const float*)d_in[0];
    const float* W_fc   = (const float*)d_in[1];
    const float* b_fc   = (const float*)d_in[2];
    const float* W_rec  = (const float*)d_in[3];
    const float* b_rec  = (const float*)d_in[4];
    const int*   rmask  = (const int*)d_in[5];
    // d_in[6] = spike_window (16)

    char* ws = (char*)d_ws;
    float* WT   = (float*)(ws);                    // 16 MB (fc, then rec)
    float* ff   = (float*)(ws + (16u << 20));      //  4 MB
    float* mem  = (float*)(ws + (20u << 20));      //  4 MB
    float* ath  = (float*)(ws + (24u << 20));      //  4 MB
    float* ssum = (float*)(ws + (28u << 20));      //  4 MB
    float* spkA = (float*)(ws + (32u << 20));      //  4 MB
    float* spkB = (float*)(ws + (36u << 20));      //  4 MB
    float* Cp   = (float*)(ws + (40u << 20));      // 16 MB (total 56 MB)

    dim3 gridT(K_IN / 32, N_OUT / 32);             // (64, 64)
    dim3 blkT(32, 8);
    dim3 gridS((B_ROWS * N_OUT) / 256);            // 4096
    dim3 gridG(N_OUT / TN, B_ROWS / TM, NPANEL);   // (16, 8, 4) = 512 blocks
    dim3 gridF((B_ROWS * N_OUT) / (256 * 4));      // 1024

    transpose_tile<<<gridT, blkT, 0, stream>>>(W_fc, rmask, WT, 0);
    init_state<<<gridS, 256, 0, stream>>>(mem, ath, ssum, spkA);
    gemm_panel<<<gridG, 128, 0, stream>>>(x, WT, Cp);
    ff_fold<<<gridF, 256, 0, stream>>>(Cp, b_fc, ff);
    transpose_tile<<<gridT, blkT, 0, stream>>>(W_rec, rmask, WT, 1);

    for (int t = 0; t < NSTEP; t++) {
        const float* si = (t & 1) ? spkB : spkA;
        float*       so = (t & 1) ? spkA : spkB;
        gemm_panel<<<gridG, 128, 0, stream>>>(si, WT, Cp);
        fold_update<<<gridF, 256, 0, stream>>>(
            Cp, b_rec, si, ff, mem, ath, ssum, so, (float*)d_out, t == NSTEP - 1);
    }
}